// Round 1
// baseline (449.129 us; speedup 1.0000x reference)
//
#include <hip/hip_runtime.h>

#define N     8192
#define FIN   256
#define FOUT  64
#define ALPHA 0.2f
#define R     16
#define TILE  512
#define WPAD  20   // 16 w values + 4 pad floats -> 80B row, keeps float4 align

// ---------------- kernel 1: h = X@W, f1 = h@a1, f2 = h@a2 ----------------
__global__ __launch_bounds__(256) void k_h(
        const float* __restrict__ X, const float* __restrict__ W,
        const float* __restrict__ a1, const float* __restrict__ a2,
        float* __restrict__ h, float* __restrict__ f1, float* __restrict__ f2) {
    const int lane = threadIdx.x & 63;
    const int wave = threadIdx.x >> 6;
    const int row0 = (blockIdx.x * 4 + wave) * 4;   // 4 rows per wave

    const float4* Xr[4];
    #pragma unroll
    for (int r = 0; r < 4; ++r)
        Xr[r] = (const float4*)(X + (size_t)(row0 + r) * FIN);

    float acc[4] = {0.f, 0.f, 0.f, 0.f};
    #pragma unroll 4
    for (int k4 = 0; k4 < FIN / 4; ++k4) {
        const float w0 = W[(k4 * 4 + 0) * FOUT + lane];
        const float w1 = W[(k4 * 4 + 1) * FOUT + lane];
        const float w2 = W[(k4 * 4 + 2) * FOUT + lane];
        const float w3 = W[(k4 * 4 + 3) * FOUT + lane];
        #pragma unroll
        for (int r = 0; r < 4; ++r) {
            const float4 xv = Xr[r][k4];
            acc[r] = fmaf(xv.x, w0, acc[r]);
            acc[r] = fmaf(xv.y, w1, acc[r]);
            acc[r] = fmaf(xv.z, w2, acc[r]);
            acc[r] = fmaf(xv.w, w3, acc[r]);
        }
    }

    const float a1v = a1[lane];
    const float a2v = a2[lane];
    #pragma unroll
    for (int r = 0; r < 4; ++r) {
        h[(size_t)(row0 + r) * FOUT + lane] = acc[r];
        float p1 = acc[r] * a1v;
        float p2 = acc[r] * a2v;
        #pragma unroll
        for (int off = 32; off > 0; off >>= 1) {
            p1 += __shfl_down(p1, off);
            p2 += __shfl_down(p2, off);
        }
        if (lane == 0) { f1[row0 + r] = p1; f2[row0 + r] = p2; }
    }
}

// ---------------- kernel 2: F2MAX = max_j f2[j] ----------------
__global__ __launch_bounds__(256) void k_max(const float* __restrict__ f2,
                                             float* __restrict__ f2max) {
    __shared__ float red[256];
    float m = -1e30f;
    for (int j = threadIdx.x; j < N; j += 256) m = fmaxf(m, f2[j]);
    red[threadIdx.x] = m;
    __syncthreads();
    #pragma unroll
    for (int s = 128; s > 0; s >>= 1) {
        if ((int)threadIdx.x < s)
            red[threadIdx.x] = fmaxf(red[threadIdx.x], red[threadIdx.x + s]);
        __syncthreads();
    }
    if (threadIdx.x == 0) *f2max = red[0];
}

// ---------------- kernel 3: masked softmax + att@h + elu ----------------
__global__ __launch_bounds__(256) void k_attn(
        const int* __restrict__ adj, const float* __restrict__ h,
        const float* __restrict__ f1, const float* __restrict__ f2,
        const float* __restrict__ f2maxp, float* __restrict__ out) {
    __shared__ float wt[TILE * WPAD];     // 40 KB: w tile, layout [jj][16 + pad]
    __shared__ float ared[R * FOUT];      // 4 KB: cross-wave acc reduction
    __shared__ float sredw[4 * R];
    __shared__ float sfin[R];

    const int t    = threadIdx.x;
    const int lane = t & 63;
    const int wv   = t >> 6;              // wave id 0..3
    const int i0   = blockIdx.x * R;
    const float F2MAX = *f2maxp;

    float f1v[R], M[R], sacc[R];
    #pragma unroll
    for (int r = 0; r < R; ++r) {
        f1v[r] = f1[i0 + r];
        const float e = f1v[r] + F2MAX;
        M[r] = (e > 0.f) ? e : ALPHA * e;   // upper bound on row scores
        sacc[r] = 0.f;
    }

    float4 acc[R];
    #pragma unroll
    for (int r = 0; r < R; ++r) acc[r] = make_float4(0.f, 0.f, 0.f, 0.f);

    const int fq   = (lane & 15) * 4;     // feature quad base (0..60)
    const int jsub = lane >> 4;           // 0..3 (j offset within step)

    for (int jt = 0; jt < N; jt += TILE) {
        // ---- phase A: compute masked exp weights into LDS ----
        #pragma unroll
        for (int c = 0; c < TILE / 256; ++c) {
            const int jj = c * 256 + t;
            const int j  = jt + jj;
            const float f2v = f2[j];
            float wloc[R];
            #pragma unroll
            for (int r = 0; r < R; ++r) {
                const int a = __builtin_nontemporal_load(&adj[(i0 + r) * N + j]);
                float e = f1v[r] + f2v;
                e = (e > 0.f) ? e : ALPHA * e;
                const float w = (a > 0) ? __expf(e - M[r]) : 0.f;
                wloc[r] = w;
                sacc[r] += w;
            }
            float4* dst = (float4*)&wt[jj * WPAD];
            dst[0] = make_float4(wloc[0],  wloc[1],  wloc[2],  wloc[3]);
            dst[1] = make_float4(wloc[4],  wloc[5],  wloc[6],  wloc[7]);
            dst[2] = make_float4(wloc[8],  wloc[9],  wloc[10], wloc[11]);
            dst[3] = make_float4(wloc[12], wloc[13], wloc[14], wloc[15]);
        }
        __syncthreads();

        // ---- phase B: acc[r] += w[r][j] * h[j][f] ----
        #pragma unroll 2
        for (int s = 0; s < 128 / 4; ++s) {
            const int jj = wv * 128 + s * 4 + jsub;   // tile-local j
            const int j  = jt + jj;
            const float4 hv = *(const float4*)&h[j * FOUT + fq];
            const float4* wr4 = (const float4*)&wt[jj * WPAD];
            float w16[16];
            *(float4*)&w16[0]  = wr4[0];
            *(float4*)&w16[4]  = wr4[1];
            *(float4*)&w16[8]  = wr4[2];
            *(float4*)&w16[12] = wr4[3];
            #pragma unroll
            for (int r = 0; r < R; ++r) {
                acc[r].x = fmaf(w16[r], hv.x, acc[r].x);
                acc[r].y = fmaf(w16[r], hv.y, acc[r].y);
                acc[r].z = fmaf(w16[r], hv.z, acc[r].z);
                acc[r].w = fmaf(w16[r], hv.w, acc[r].w);
            }
        }
        __syncthreads();
    }

    // ---- reduce softmax denominators (all 256 threads hold partials) ----
    #pragma unroll
    for (int r = 0; r < R; ++r) {
        float v = sacc[r];
        #pragma unroll
        for (int off = 32; off > 0; off >>= 1) v += __shfl_down(v, off);
        if (lane == 0) sredw[wv * R + r] = v;
    }
    __syncthreads();
    if (t < R) {
        const float sv = sredw[t] + sredw[R + t] + sredw[2 * R + t] + sredw[3 * R + t];
        sfin[t] = fmaxf(sv, 1e-30f);
    }
    __syncthreads();

    // ---- reduce acc across waves (4 rows per round), normalize, elu ----
    const int rr_e = t >> 6;
    const int fcol = t & 63;
    #pragma unroll
    for (int q = 0; q < 4; ++q) {
        #pragma unroll
        for (int rr = 0; rr < 4; ++rr) {
            float4 v = acc[q * 4 + rr];
            v.x += __shfl_down(v.x, 32); v.x += __shfl_down(v.x, 16);
            v.y += __shfl_down(v.y, 32); v.y += __shfl_down(v.y, 16);
            v.z += __shfl_down(v.z, 32); v.z += __shfl_down(v.z, 16);
            v.w += __shfl_down(v.w, 32); v.w += __shfl_down(v.w, 16);
            if (lane < 16)
                *(float4*)&ared[(wv * 4 + rr) * FOUT + lane * 4] = v;
        }
        __syncthreads();
        {
            const int r = q * 4 + rr_e;
            const float v = ared[(0 * 4 + rr_e) * FOUT + fcol]
                          + ared[(1 * 4 + rr_e) * FOUT + fcol]
                          + ared[(2 * 4 + rr_e) * FOUT + fcol]
                          + ared[(3 * 4 + rr_e) * FOUT + fcol];
            const float hp = __fdividef(v, sfin[r]);
            out[(i0 + r) * FOUT + fcol] = (hp > 0.f) ? hp : (__expf(hp) - 1.f);
        }
        __syncthreads();
    }
}

extern "C" void kernel_launch(void* const* d_in, const int* in_sizes, int n_in,
                              void* d_out, int out_size, void* d_ws, size_t ws_size,
                              hipStream_t stream) {
    const float* X   = (const float*)d_in[0];
    const int*   adj = (const int*)d_in[1];
    const float* W   = (const float*)d_in[2];
    const float* a1  = (const float*)d_in[3];
    const float* a2  = (const float*)d_in[4];
    float* out = (float*)d_out;

    float* h   = (float*)d_ws;                  // N*FOUT floats
    float* f1  = h + (size_t)N * FOUT;          // N floats
    float* f2  = f1 + N;                        // N floats
    float* f2m = f2 + N;                        // 1 float

    k_h  <<<N / 16, 256, 0, stream>>>(X, W, a1, a2, h, f1, f2);
    k_max<<<1,      256, 0, stream>>>(f2, f2m);
    k_attn<<<N / R, 256, 0, stream>>>(adj, h, f1, f2, f2m, out);
}

// Round 2
// 228.798 us; speedup vs baseline: 1.9630x; 1.9630x over previous
//
#include <hip/hip_runtime.h>

#define N     8192
#define FIN   256
#define FOUT  64
#define ALPHA 0.2f
#define R     8          // rows per block
#define TILE  512        // j-tile
#define NCH   (TILE/256) // chunks per tile in phase A
#define WPAD  12         // 8 w values + 4 pad -> 48B row, float4-aligned

// ---------------- kernel 1: h = X@W, f1 = h@a1, f2 = h@a2 ----------------
__global__ __launch_bounds__(256) void k_h(
        const float* __restrict__ X, const float* __restrict__ W,
        const float* __restrict__ a1, const float* __restrict__ a2,
        float* __restrict__ h, float* __restrict__ f1, float* __restrict__ f2) {
    const int lane = threadIdx.x & 63;
    const int wave = threadIdx.x >> 6;
    const int row0 = (blockIdx.x * 4 + wave) * 4;   // 4 rows per wave

    const float4* Xr[4];
    #pragma unroll
    for (int r = 0; r < 4; ++r)
        Xr[r] = (const float4*)(X + (size_t)(row0 + r) * FIN);

    float acc[4] = {0.f, 0.f, 0.f, 0.f};
    #pragma unroll 4
    for (int k4 = 0; k4 < FIN / 4; ++k4) {
        const float w0 = W[(k4 * 4 + 0) * FOUT + lane];
        const float w1 = W[(k4 * 4 + 1) * FOUT + lane];
        const float w2 = W[(k4 * 4 + 2) * FOUT + lane];
        const float w3 = W[(k4 * 4 + 3) * FOUT + lane];
        #pragma unroll
        for (int r = 0; r < 4; ++r) {
            const float4 xv = Xr[r][k4];
            acc[r] = fmaf(xv.x, w0, acc[r]);
            acc[r] = fmaf(xv.y, w1, acc[r]);
            acc[r] = fmaf(xv.z, w2, acc[r]);
            acc[r] = fmaf(xv.w, w3, acc[r]);
        }
    }

    const float a1v = a1[lane];
    const float a2v = a2[lane];
    #pragma unroll
    for (int r = 0; r < 4; ++r) {
        h[(size_t)(row0 + r) * FOUT + lane] = acc[r];
        float p1 = acc[r] * a1v;
        float p2 = acc[r] * a2v;
        #pragma unroll
        for (int off = 32; off > 0; off >>= 1) {
            p1 += __shfl_down(p1, off);
            p2 += __shfl_down(p2, off);
        }
        if (lane == 0) { f1[row0 + r] = p1; f2[row0 + r] = p2; }
    }
}

// ---------------- kernel 2: F2MAX = max_j f2[j] ----------------
__global__ __launch_bounds__(256) void k_max(const float* __restrict__ f2,
                                             float* __restrict__ f2max) {
    __shared__ float red[256];
    float m = -1e30f;
    for (int j = threadIdx.x; j < N; j += 256) m = fmaxf(m, f2[j]);
    red[threadIdx.x] = m;
    __syncthreads();
    #pragma unroll
    for (int s = 128; s > 0; s >>= 1) {
        if ((int)threadIdx.x < s)
            red[threadIdx.x] = fmaxf(red[threadIdx.x], red[threadIdx.x + s]);
        __syncthreads();
    }
    if (threadIdx.x == 0) *f2max = red[0];
}

// ---------------- kernel 3: masked softmax + att@h + elu ----------------
__global__ __launch_bounds__(256, 4) void k_attn(
        const int* __restrict__ adj, const float* __restrict__ h,
        const float* __restrict__ f1, const float* __restrict__ f2,
        const float* __restrict__ f2maxp, float* __restrict__ out) {
    __shared__ float wt[(TILE + 8) * WPAD];   // ~25 KB w tile (+pad rows for pipeline)
    __shared__ float ared[4 * R * FOUT];      // 8 KB cross-wave acc reduction
    __shared__ float sredw[4 * R];
    __shared__ float sfin[R];

    const int t    = threadIdx.x;
    const int lane = t & 63;
    const int wv   = t >> 6;
    const int i0   = blockIdx.x * R;
    const float F2MAX = *f2maxp;

    float f1v[R], M[R], sacc[R];
    #pragma unroll
    for (int r = 0; r < R; ++r) {
        f1v[r] = f1[i0 + r];
        const float e = f1v[r] + F2MAX;
        M[r] = (e > 0.f) ? e : ALPHA * e;   // upper bound on row scores (exact shift)
        sacc[r] = 0.f;
    }

    float4 acc[R];
    #pragma unroll
    for (int r = 0; r < R; ++r) acc[r] = make_float4(0.f, 0.f, 0.f, 0.f);

    const int fq   = (lane & 15) * 4;     // feature quad base
    const int jsub = lane >> 4;           // 0..3

    // ---- prologue: prefetch adj for tile 0 into registers ----
    int areg[NCH][R];
    #pragma unroll
    for (int c = 0; c < NCH; ++c)
        #pragma unroll
        for (int r = 0; r < R; ++r)
            areg[c][r] = __builtin_nontemporal_load(
                &adj[(size_t)(i0 + r) * N + c * 256 + t]);

    for (int jt = 0; jt < N; jt += TILE) {
        const int jtn = (jt + TILE < N) ? jt + TILE : 0;   // wrap: loads unused

        // ---- phase A: masked exp weights -> LDS; prefetch next tile's adj ----
        #pragma unroll
        for (int c = 0; c < NCH; ++c) {
            const int jj = c * 256 + t;
            const float f2v = f2[jt + jj];
            float wloc[R];
            #pragma unroll
            for (int r = 0; r < R; ++r) {
                const int a = areg[c][r];
                areg[c][r] = __builtin_nontemporal_load(
                    &adj[(size_t)(i0 + r) * N + jtn + jj]);   // prefetch next tile
                float e = f1v[r] + f2v;
                e = (e > 0.f) ? e : ALPHA * e;
                const float w = (a > 0) ? __expf(e - M[r]) : 0.f;
                wloc[r] = w;
                sacc[r] += w;
            }
            float4* dst = (float4*)&wt[jj * WPAD];
            dst[0] = make_float4(wloc[0], wloc[1], wloc[2], wloc[3]);
            dst[1] = make_float4(wloc[4], wloc[5], wloc[6], wloc[7]);
        }
        __syncthreads();

        // ---- phase B: acc[r] += w[r][j] * h[j][f], 2-stage pipelined ----
        {
            int jj = wv * 128 + jsub;
            float4 hv = *(const float4*)&h[(size_t)(jt + jj) * FOUT + fq];
            float4 wa = *(const float4*)&wt[jj * WPAD];
            float4 wb = *(const float4*)&wt[jj * WPAD + 4];
            #pragma unroll 4
            for (int s = 0; s < 32; ++s) {
                const int sn  = (s + 1 < 32) ? s + 1 : s;      // guarded prefetch
                const int jjn = wv * 128 + sn * 4 + jsub;
                float4 hvn = *(const float4*)&h[(size_t)(jt + jjn) * FOUT + fq];
                float4 wan = *(const float4*)&wt[jjn * WPAD];
                float4 wbn = *(const float4*)&wt[jjn * WPAD + 4];

                acc[0].x = fmaf(wa.x, hv.x, acc[0].x); acc[0].y = fmaf(wa.x, hv.y, acc[0].y);
                acc[0].z = fmaf(wa.x, hv.z, acc[0].z); acc[0].w = fmaf(wa.x, hv.w, acc[0].w);
                acc[1].x = fmaf(wa.y, hv.x, acc[1].x); acc[1].y = fmaf(wa.y, hv.y, acc[1].y);
                acc[1].z = fmaf(wa.y, hv.z, acc[1].z); acc[1].w = fmaf(wa.y, hv.w, acc[1].w);
                acc[2].x = fmaf(wa.z, hv.x, acc[2].x); acc[2].y = fmaf(wa.z, hv.y, acc[2].y);
                acc[2].z = fmaf(wa.z, hv.z, acc[2].z); acc[2].w = fmaf(wa.z, hv.w, acc[2].w);
                acc[3].x = fmaf(wa.w, hv.x, acc[3].x); acc[3].y = fmaf(wa.w, hv.y, acc[3].y);
                acc[3].z = fmaf(wa.w, hv.z, acc[3].z); acc[3].w = fmaf(wa.w, hv.w, acc[3].w);
                acc[4].x = fmaf(wb.x, hv.x, acc[4].x); acc[4].y = fmaf(wb.x, hv.y, acc[4].y);
                acc[4].z = fmaf(wb.x, hv.z, acc[4].z); acc[4].w = fmaf(wb.x, hv.w, acc[4].w);
                acc[5].x = fmaf(wb.y, hv.x, acc[5].x); acc[5].y = fmaf(wb.y, hv.y, acc[5].y);
                acc[5].z = fmaf(wb.y, hv.z, acc[5].z); acc[5].w = fmaf(wb.y, hv.w, acc[5].w);
                acc[6].x = fmaf(wb.z, hv.x, acc[6].x); acc[6].y = fmaf(wb.z, hv.y, acc[6].y);
                acc[6].z = fmaf(wb.z, hv.z, acc[6].z); acc[6].w = fmaf(wb.z, hv.w, acc[6].w);
                acc[7].x = fmaf(wb.w, hv.x, acc[7].x); acc[7].y = fmaf(wb.w, hv.y, acc[7].y);
                acc[7].z = fmaf(wb.w, hv.z, acc[7].z); acc[7].w = fmaf(wb.w, hv.w, acc[7].w);

                hv = hvn; wa = wan; wb = wbn;
            }
        }
        __syncthreads();
    }

    // ---- reduce softmax denominators ----
    #pragma unroll
    for (int r = 0; r < R; ++r) {
        float v = sacc[r];
        #pragma unroll
        for (int off = 32; off > 0; off >>= 1) v += __shfl_down(v, off);
        if (lane == 0) sredw[wv * R + r] = v;
    }
    __syncthreads();
    if (t < R) {
        const float sv = sredw[t] + sredw[R + t] + sredw[2 * R + t] + sredw[3 * R + t];
        sfin[t] = fmaxf(sv, 1e-30f);
    }
    __syncthreads();

    // ---- reduce acc across jsub (shfl) then across waves (LDS) ----
    #pragma unroll
    for (int r = 0; r < R; ++r) {
        float4 v = acc[r];
        v.x += __shfl_down(v.x, 32); v.x += __shfl_down(v.x, 16);
        v.y += __shfl_down(v.y, 32); v.y += __shfl_down(v.y, 16);
        v.z += __shfl_down(v.z, 32); v.z += __shfl_down(v.z, 16);
        v.w += __shfl_down(v.w, 32); v.w += __shfl_down(v.w, 16);
        if (lane < 16)
            *(float4*)&ared[(wv * R + r) * FOUT + lane * 4] = v;
    }
    __syncthreads();

    const int fcol = t & 63;
    #pragma unroll
    for (int q = 0; q < 2; ++q) {
        const int r = q * 4 + (t >> 6);
        const float v = ared[(0 * R + r) * FOUT + fcol]
                      + ared[(1 * R + r) * FOUT + fcol]
                      + ared[(2 * R + r) * FOUT + fcol]
                      + ared[(3 * R + r) * FOUT + fcol];
        const float hp = __fdividef(v, sfin[r]);
        out[(size_t)(i0 + r) * FOUT + fcol] = (hp > 0.f) ? hp : (__expf(hp) - 1.f);
    }
}

extern "C" void kernel_launch(void* const* d_in, const int* in_sizes, int n_in,
                              void* d_out, int out_size, void* d_ws, size_t ws_size,
                              hipStream_t stream) {
    const float* X   = (const float*)d_in[0];
    const int*   adj = (const int*)d_in[1];
    const float* W   = (const float*)d_in[2];
    const float* a1  = (const float*)d_in[3];
    const float* a2  = (const float*)d_in[4];
    float* out = (float*)d_out;

    float* h   = (float*)d_ws;                  // N*FOUT floats
    float* f1  = h + (size_t)N * FOUT;          // N floats
    float* f2  = f1 + N;                        // N floats
    float* f2m = f2 + N;                        // 1 float

    k_h  <<<N / 16, 256, 0, stream>>>(X, W, a1, a2, h, f1, f2);
    k_max<<<1,      256, 0, stream>>>(f2, f2m);
    k_attn<<<N / R, 256, 0, stream>>>(adj, h, f1, f2, f2m, out);
}

// Round 4
// 184.524 us; speedup vs baseline: 2.4340x; 1.2399x over previous
//
#include <hip/hip_runtime.h>

#define N     8192
#define FIN   256
#define FOUT  64
#define ALPHA 0.2f
#define R     16          // rows per block (one 16x16x32 MFMA M-tile)
#define TILE  256         // j-tile (K per iteration = 256 = 8 MFMA K-steps)

typedef __attribute__((ext_vector_type(8))) short bf16x8;
typedef __attribute__((ext_vector_type(4))) float f32x4;
typedef __attribute__((ext_vector_type(4))) int   i32x4;

static __device__ __forceinline__ unsigned short f2bf(float x) {
    union { float f; unsigned int u; } v; v.f = x;
    unsigned int r = v.u + 0x7FFFu + ((v.u >> 16) & 1u);   // RNE
    return (unsigned short)(r >> 16);
}
static __device__ __forceinline__ float bf2f(unsigned short b) {
    union { float f; unsigned int u; } v; v.u = ((unsigned int)b) << 16;
    return v.f;
}

// ------- kernel 1: h = X@W (bf16, transposed -> h_t[64][N]), f1, f2 -------
__global__ __launch_bounds__(256) void k_h(
        const float* __restrict__ X, const float* __restrict__ W,
        const float* __restrict__ a1, const float* __restrict__ a2,
        unsigned short* __restrict__ h_t,
        float* __restrict__ f1, float* __restrict__ f2) {
    const int lane = threadIdx.x & 63;
    const int wave = threadIdx.x >> 6;
    const int row0 = (blockIdx.x * 4 + wave) * 4;   // 4 rows per wave

    const float4* Xr[4];
    #pragma unroll
    for (int r = 0; r < 4; ++r)
        Xr[r] = (const float4*)(X + (size_t)(row0 + r) * FIN);

    float acc[4] = {0.f, 0.f, 0.f, 0.f};
    #pragma unroll 4
    for (int k4 = 0; k4 < FIN / 4; ++k4) {
        const float w0 = W[(k4 * 4 + 0) * FOUT + lane];
        const float w1 = W[(k4 * 4 + 1) * FOUT + lane];
        const float w2 = W[(k4 * 4 + 2) * FOUT + lane];
        const float w3 = W[(k4 * 4 + 3) * FOUT + lane];
        #pragma unroll
        for (int r = 0; r < 4; ++r) {
            const float4 xv = Xr[r][k4];
            acc[r] = fmaf(xv.x, w0, acc[r]);
            acc[r] = fmaf(xv.y, w1, acc[r]);
            acc[r] = fmaf(xv.z, w2, acc[r]);
            acc[r] = fmaf(xv.w, w3, acc[r]);
        }
    }

    // h_t[col=lane][row0..row0+3] as bf16 (one 8B store per thread)
    ushort4 hv;
    hv.x = f2bf(acc[0]); hv.y = f2bf(acc[1]);
    hv.z = f2bf(acc[2]); hv.w = f2bf(acc[3]);
    *(ushort4*)&h_t[(size_t)lane * N + row0] = hv;

    const float a1v = a1[lane];
    const float a2v = a2[lane];
    #pragma unroll
    for (int r = 0; r < 4; ++r) {
        float p1 = acc[r] * a1v;
        float p2 = acc[r] * a2v;
        #pragma unroll
        for (int off = 32; off > 0; off >>= 1) {
            p1 += __shfl_down(p1, off);
            p2 += __shfl_down(p2, off);
        }
        if (lane == 0) { f1[row0 + r] = p1; f2[row0 + r] = p2; }
    }
}

// ---------------- kernel 2: F2MAX = max_j f2[j] ----------------
__global__ __launch_bounds__(256) void k_max(const float* __restrict__ f2,
                                             float* __restrict__ f2max) {
    __shared__ float red[256];
    float m = -1e30f;
    for (int j = threadIdx.x; j < N; j += 256) m = fmaxf(m, f2[j]);
    red[threadIdx.x] = m;
    __syncthreads();
    #pragma unroll
    for (int s = 128; s > 0; s >>= 1) {
        if ((int)threadIdx.x < s)
            red[threadIdx.x] = fmaxf(red[threadIdx.x], red[threadIdx.x + s]);
        __syncthreads();
    }
    if (threadIdx.x == 0) *f2max = red[0];
}

// -------- kernel 3: masked softmax weights (bf16) + MFMA att@h + elu --------
__global__ __launch_bounds__(256, 2) void k_attn(
        const int* __restrict__ adj, const unsigned short* __restrict__ h_t,
        const float* __restrict__ f1, const float* __restrict__ f2,
        const float* __restrict__ f2maxp, float* __restrict__ out) {
    // double-buffered w tile: [buf][row][256 j as bf16], XOR-swizzled 16B chunks
    __shared__ unsigned short wlds[2][R * TILE];   // 2 x 8 KB
    __shared__ float sden[R];

    const int t    = threadIdx.x;
    const int lane = t & 63;
    const int wv   = t >> 6;
    const int i0   = blockIdx.x * R;

    // phase A mapping: thread owns (row = t>>4, 16 j's in 4 strided int4 chunks)
    const int arow = t >> 4;
    const int ajg  = t & 15;
    const float F2MAX = *f2maxp;
    const float f1v = f1[i0 + arow];
    float eM = f1v + F2MAX;
    eM = (eM > 0.f) ? eM : ALPHA * eM;    // exact softmax shift (upper bound)
    float sacc = 0.f;

    // phase B mapping (MFMA 16x16x32): lane -> A row / B col, k-group
    const int brow = lane & 15;
    const int bkg  = lane >> 4;           // 0..3
    const size_t bcol = (size_t)(wv * 16 + brow);
    const int sw = arow & 7;
    const int swr = brow & 7;

    f32x4 acc = {0.f, 0.f, 0.f, 0.f};

    const int* adj_row = adj + (size_t)(i0 + arow) * N;

    // prologue: prefetch adj tile 0 (coalesced 16B per lane)
    i32x4 areg[4];
    #pragma unroll
    for (int c = 0; c < 4; ++c)
        areg[c] = __builtin_nontemporal_load(
            (const i32x4*)(adj_row + ajg * 4 + c * 64));

    int p = 0;
    for (int jt = 0; jt < N; jt += TILE, p ^= 1) {
        // B-fragment prefetch (h_t is L2-resident; hides under phase A)
        bf16x8 bfr[8];
        #pragma unroll
        for (int ks = 0; ks < 8; ++ks)
            bfr[ks] = *(const bf16x8*)&h_t[bcol * N + jt + ks * 32 + bkg * 8];

        const int jtn = (jt + TILE < N) ? (jt + TILE) : 0;

        // ---- phase A: w = mask * exp(lrelu(f1+f2) - M) -> bf16 -> LDS ----
        #pragma unroll
        for (int c = 0; c < 4; ++c) {
            const i32x4 av = areg[c];
            areg[c] = __builtin_nontemporal_load(
                (const i32x4*)(adj_row + jtn + ajg * 4 + c * 64));  // next tile
            const int jl = ajg * 4 + c * 64;
            const float4 f2v = *(const float4*)&f2[jt + jl];

            float e0 = f1v + f2v.x; e0 = (e0 > 0.f) ? e0 : ALPHA * e0;
            float e1 = f1v + f2v.y; e1 = (e1 > 0.f) ? e1 : ALPHA * e1;
            float e2 = f1v + f2v.z; e2 = (e2 > 0.f) ? e2 : ALPHA * e2;
            float e3 = f1v + f2v.w; e3 = (e3 > 0.f) ? e3 : ALPHA * e3;

            const unsigned short b0 = (av.x > 0) ? f2bf(__expf(e0 - eM)) : 0;
            const unsigned short b1 = (av.y > 0) ? f2bf(__expf(e1 - eM)) : 0;
            const unsigned short b2 = (av.z > 0) ? f2bf(__expf(e2 - eM)) : 0;
            const unsigned short b3 = (av.w > 0) ? f2bf(__expf(e3 - eM)) : 0;

            // denominator from the ROUNDED weights (consistent with numerator)
            sacc += bf2f(b0) + bf2f(b1) + bf2f(b2) + bf2f(b3);

            const int ch   = (jl >> 3) ^ sw;       // 16B-chunk XOR swizzle
            const int half = (jl >> 2) & 1;
            uint2 uv;
            uv.x = (unsigned int)b0 | ((unsigned int)b1 << 16);
            uv.y = (unsigned int)b2 | ((unsigned int)b3 << 16);
            *(uint2*)&wlds[p][arow * TILE + ch * 8 + half * 4] = uv;
        }
        __syncthreads();

        // ---- phase B: 8 K-steps of mfma_f32_16x16x32_bf16 ----
        #pragma unroll
        for (int ks = 0; ks < 8; ++ks) {
            const int ch = (ks * 4 + bkg) ^ swr;
            const bf16x8 af = *(const bf16x8*)&wlds[p][brow * TILE + ch * 8];
            acc = __builtin_amdgcn_mfma_f32_16x16x32_bf16(af, bfr[ks], acc, 0, 0, 0);
        }
        // no trailing barrier: double buffer + next iteration's barrier protect
    }

    // ---- denominators: row's 16 threads are one 16-lane group ----
    float s = sacc;
    s += __shfl_xor(s, 1);
    s += __shfl_xor(s, 2);
    s += __shfl_xor(s, 4);
    s += __shfl_xor(s, 8);
    if (ajg == 0) sden[arow] = fmaxf(s, 1e-30f);
    __syncthreads();

    // ---- normalize + ELU + store (C/D: col=lane&15, row=(lane>>4)*4+reg) ----
    #pragma unroll
    for (int rg = 0; rg < 4; ++rg) {
        const int orow = bkg * 4 + rg;
        const float hp = acc[rg] / sden[orow];
        const float o = (hp > 0.f) ? hp : (__expf(hp) - 1.f);
        out[(size_t)(i0 + orow) * FOUT + bcol] = o;
    }
}

extern "C" void kernel_launch(void* const* d_in, const int* in_sizes, int n_in,
                              void* d_out, int out_size, void* d_ws, size_t ws_size,
                              hipStream_t stream) {
    const float* X   = (const float*)d_in[0];
    const int*   adj = (const int*)d_in[1];
    const float* W   = (const float*)d_in[2];
    const float* a1  = (const float*)d_in[3];
    const float* a2  = (const float*)d_in[4];
    float* out = (float*)d_out;

    unsigned short* h_t = (unsigned short*)d_ws;          // 64*N bf16 = 1 MB
    float* f1  = (float*)((char*)d_ws + (size_t)FOUT * N * 2);
    float* f2  = f1 + N;
    float* f2m = f2 + N;

    k_h  <<<N / 16, 256, 0, stream>>>(X, W, a1, a2, h_t, f1, f2);
    k_max<<<1,      256, 0, stream>>>(f2, f2m);
    k_attn<<<N / R, 256, 0, stream>>>(adj, h_t, f1, f2, f2m, out);
}

// Round 5
// 141.099 us; speedup vs baseline: 3.1831x; 1.3078x over previous
//
#include <hip/hip_runtime.h>

#define N     8192
#define FIN   256
#define FOUT  64
#define ALPHA 0.2f
#define KQ    4               // K-split across blocks
#define JQ    (N / KQ)        // 2048 j per block
#define NIT   (JQ / 256)      // 8 iterations (4 waves x 64 j each)

typedef __attribute__((ext_vector_type(8))) short bf16x8;
typedef __attribute__((ext_vector_type(4))) float f32x4;
typedef __attribute__((ext_vector_type(4))) int   i32x4;

static __device__ __forceinline__ unsigned short f2bf(float x) {
    union { float f; unsigned int u; } v; v.f = x;
    unsigned int r = v.u + 0x7FFFu + ((v.u >> 16) & 1u);   // RNE
    return (unsigned short)(r >> 16);
}
static __device__ __forceinline__ float bf2f(unsigned short b) {
    union { float f; unsigned int u; } v; v.u = ((unsigned int)b) << 16;
    return v.f;
}
// masked exp(leaky_relu(f1+f2)) — no softmax shift needed (scores <= ~15)
static __device__ __forceinline__ float wcalc(float f1v, float f2v, int a) {
    float e = f1v + f2v;
    e = (e > 0.f) ? e : ALPHA * e;
    const float w = __expf(e);
    return (a > 0) ? w : 0.f;
}

// ------- kernel 1: h = X@W (bf16, transposed -> h_t[64][N]), f1, f2 -------
__global__ __launch_bounds__(256) void k_h(
        const float* __restrict__ X, const float* __restrict__ W,
        const float* __restrict__ a1, const float* __restrict__ a2,
        unsigned short* __restrict__ h_t,
        float* __restrict__ f1, float* __restrict__ f2) {
    const int lane = threadIdx.x & 63;
    const int wave = threadIdx.x >> 6;
    const int row0 = (blockIdx.x * 4 + wave) * 4;

    const float4* Xr[4];
    #pragma unroll
    for (int r = 0; r < 4; ++r)
        Xr[r] = (const float4*)(X + (size_t)(row0 + r) * FIN);

    float acc[4] = {0.f, 0.f, 0.f, 0.f};
    #pragma unroll 4
    for (int k4 = 0; k4 < FIN / 4; ++k4) {
        const float w0 = W[(k4 * 4 + 0) * FOUT + lane];
        const float w1 = W[(k4 * 4 + 1) * FOUT + lane];
        const float w2 = W[(k4 * 4 + 2) * FOUT + lane];
        const float w3 = W[(k4 * 4 + 3) * FOUT + lane];
        #pragma unroll
        for (int r = 0; r < 4; ++r) {
            const float4 xv = Xr[r][k4];
            acc[r] = fmaf(xv.x, w0, acc[r]);
            acc[r] = fmaf(xv.y, w1, acc[r]);
            acc[r] = fmaf(xv.z, w2, acc[r]);
            acc[r] = fmaf(xv.w, w3, acc[r]);
        }
    }

    ushort4 hv;
    hv.x = f2bf(acc[0]); hv.y = f2bf(acc[1]);
    hv.z = f2bf(acc[2]); hv.w = f2bf(acc[3]);
    *(ushort4*)&h_t[(size_t)lane * N + row0] = hv;

    const float a1v = a1[lane];
    const float a2v = a2[lane];
    #pragma unroll
    for (int r = 0; r < 4; ++r) {
        float p1 = acc[r] * a1v;
        float p2 = acc[r] * a2v;
        #pragma unroll
        for (int off = 32; off > 0; off >>= 1) {
            p1 += __shfl_down(p1, off);
            p2 += __shfl_down(p2, off);
        }
        if (lane == 0) { f1[row0 + r] = p1; f2[row0 + r] = p2; }
    }
}

// -------- kernel 2: barrier-free MFMA attention partial sums --------
// block b: row-group b>>2 (16 rows), j-quarter b&3. 4 waves split each
// 256-j iteration; each wave builds its A-frag (exp weights) in registers.
__global__ __launch_bounds__(256, 6) void k_attn(
        const int* __restrict__ adj, const unsigned short* __restrict__ h_t,
        const float* __restrict__ f1, const float* __restrict__ f2,
        float* __restrict__ part, float* __restrict__ pden) {
    __shared__ f32x4 red[2][256];    // 8 KB end-of-kernel acc staging
    __shared__ float dred[4][16];

    const int t    = threadIdx.x;
    const int lane = t & 63;
    const int wv   = t >> 6;
    const int bid  = blockIdx.x;
    const int rg   = bid >> 2;
    const int q    = bid & 3;
    const int i0   = rg * 16;
    const int r    = lane & 15;     // A-row / B-col-sub / output col
    const int kg   = lane >> 4;     // k-group within K-step

    const float f1v = f1[i0 + r];
    const int jbase = q * JQ + wv * 64 + kg * 8;
    const int* aptr = adj + (size_t)(i0 + r) * N + jbase;
    const float* f2p = f2 + jbase;

    f32x4 acc[4];
    #pragma unroll
    for (int c = 0; c < 4; ++c) acc[c] = (f32x4){0.f, 0.f, 0.f, 0.f};
    float sacc = 0.f;

    // adj prefetch, one iteration deep (4 x 16B per lane per iter)
    i32x4 apf[4];
    #pragma unroll
    for (int u = 0; u < 4; ++u)
        apf[u] = *(const i32x4*)(aptr + (u >> 1) * 32 + (u & 1) * 4);

    for (int it = 0; it < NIT; ++it) {
        i32x4 acur[4];
        #pragma unroll
        for (int u = 0; u < 4; ++u) acur[u] = apf[u];
        const int noff = ((it + 1) & (NIT - 1)) * 256;   // wrap: extra reads unused
        #pragma unroll
        for (int u = 0; u < 4; ++u)
            apf[u] = *(const i32x4*)(aptr + noff + (u >> 1) * 32 + (u & 1) * 4);

        #pragma unroll
        for (int ks = 0; ks < 2; ++ks) {
            const int off = it * 256 + ks * 32;
            const float4 fa = *(const float4*)(f2p + off);
            const float4 fb = *(const float4*)(f2p + off + 4);
            const i32x4 a0 = acur[ks * 2 + 0];
            const i32x4 a1 = acur[ks * 2 + 1];

            float w[8];
            w[0] = wcalc(f1v, fa.x, a0.x);
            w[1] = wcalc(f1v, fa.y, a0.y);
            w[2] = wcalc(f1v, fa.z, a0.z);
            w[3] = wcalc(f1v, fa.w, a0.w);
            w[4] = wcalc(f1v, fb.x, a1.x);
            w[5] = wcalc(f1v, fb.y, a1.y);
            w[6] = wcalc(f1v, fb.z, a1.z);
            w[7] = wcalc(f1v, fb.w, a1.w);

            bf16x8 af;
            float ds = 0.f;
            #pragma unroll
            for (int u = 0; u < 8; ++u) {
                const unsigned short b = f2bf(w[u]);
                af[u] = (short)b;
                ds += bf2f(b);          // denominator from ROUNDED weights
            }
            sacc += ds;

            #pragma unroll
            for (int cg = 0; cg < 4; ++cg) {
                const bf16x8 bf = *(const bf16x8*)
                    &h_t[(size_t)(cg * 16 + r) * N + jbase + off];
                acc[cg] = __builtin_amdgcn_mfma_f32_16x16x32_bf16(
                    af, bf, acc[cg], 0, 0, 0);
            }
        }
    }

    // ---- denominator: sum lanes sharing the same row (l, l+16, l+32, l+48) ----
    sacc += __shfl_xor(sacc, 16);
    sacc += __shfl_xor(sacc, 32);
    if (lane < 16) dred[wv][lane] = sacc;

    // ---- acc tree-reduce across the 4 waves ----
    __syncthreads();
    if (wv >= 2) {
        #pragma unroll
        for (int cg = 0; cg < 4; ++cg) red[wv - 2][lane * 4 + cg] = acc[cg];
    }
    __syncthreads();
    if (wv < 2) {
        #pragma unroll
        for (int cg = 0; cg < 4; ++cg) acc[cg] += red[wv][lane * 4 + cg];
    }
    __syncthreads();
    if (wv == 1) {
        #pragma unroll
        for (int cg = 0; cg < 4; ++cg) red[0][lane * 4 + cg] = acc[cg];
    }
    __syncthreads();
    if (wv == 0) {
        #pragma unroll
        for (int cg = 0; cg < 4; ++cg) acc[cg] += red[0][lane * 4 + cg];
        // C/D layout: col = cg*16 + (lane&15), row = (lane>>4)*4 + reg
        #pragma unroll
        for (int cg = 0; cg < 4; ++cg)
            #pragma unroll
            for (int rr = 0; rr < 4; ++rr)
                part[(size_t)bid * 1024 + (kg * 4 + rr) * FOUT + cg * 16 + r]
                    = acc[cg][rr];
        if (lane < 16)
            pden[bid * 16 + lane] =
                dred[0][lane] + dred[1][lane] + dred[2][lane] + dred[3][lane];
    }
}

// -------- kernel 3: combine 4 partials, normalize, ELU --------
__global__ __launch_bounds__(256) void k_fin(
        const float* __restrict__ part, const float* __restrict__ pden,
        float* __restrict__ out) {
    const int rg = blockIdx.x;
    const int t  = threadIdx.x;
    const int r  = t >> 4;
    const int c4 = (t & 15) * 4;

    float4 v = make_float4(0.f, 0.f, 0.f, 0.f);
    float den = 0.f;
    #pragma unroll
    for (int p = 0; p < 4; ++p) {
        const float4 pv = *(const float4*)
            &part[(size_t)((rg * 4 + p) * 16 + r) * FOUT + c4];
        v.x += pv.x; v.y += pv.y; v.z += pv.z; v.w += pv.w;
        den += pden[(rg * 4 + p) * 16 + r];
    }
    den = fmaxf(den, 1e-30f);
    const float inv = __fdividef(1.f, den);
    float4 o;
    const float h0 = v.x * inv; o.x = (h0 > 0.f) ? h0 : (__expf(h0) - 1.f);
    const float h1 = v.y * inv; o.y = (h1 > 0.f) ? h1 : (__expf(h1) - 1.f);
    const float h2 = v.z * inv; o.z = (h2 > 0.f) ? h2 : (__expf(h2) - 1.f);
    const float h3 = v.w * inv; o.w = (h3 > 0.f) ? h3 : (__expf(h3) - 1.f);
    *(float4*)&out[(size_t)(rg * 16 + r) * FOUT + c4] = o;
}

extern "C" void kernel_launch(void* const* d_in, const int* in_sizes, int n_in,
                              void* d_out, int out_size, void* d_ws, size_t ws_size,
                              hipStream_t stream) {
    const float* X   = (const float*)d_in[0];
    const int*   adj = (const int*)d_in[1];
    const float* W   = (const float*)d_in[2];
    const float* a1  = (const float*)d_in[3];
    const float* a2  = (const float*)d_in[4];
    float* out = (float*)d_out;

    unsigned short* h_t = (unsigned short*)d_ws;                  // 1 MB
    float* f1   = (float*)((char*)d_ws + (size_t)FOUT * N * 2);   // N floats
    float* f2   = f1 + N;                                         // N floats
    float* part = f2 + N;                                         // 2048*1024 floats
    float* pden = part + (size_t)512 * KQ * 1024;                 // 2048*16 floats

    k_h   <<<N / 16, 256, 0, stream>>>(X, W, a1, a2, h_t, f1, f2);
    k_attn<<<(N / 16) * KQ, 256, 0, stream>>>(adj, h_t, f1, f2, part, pden);
    k_fin <<<N / 16, 256, 0, stream>>>(part, pden, out);
}

// Round 6
// 110.231 us; speedup vs baseline: 4.0744x; 1.2800x over previous
//
#include <hip/hip_runtime.h>
#include <hip/hip_bf16.h>

#define N     8192
#define FIN   256
#define FOUT  64
#define ALPHA 0.2f
#define KQ    8               // j-split across blocks
#define JQ    (N / KQ)        // 1024 j per block
#define JW    (JQ / 4)        // 256 j per wave
#define NS    (JW / 32)       // 8 MFMA K-steps per wave

typedef __attribute__((ext_vector_type(8))) short bf16x8;
typedef __attribute__((ext_vector_type(4))) float f32x4;
typedef __attribute__((ext_vector_type(4))) int   i32x4;

static __device__ __forceinline__ unsigned short f2bf(float x) {
    union { float f; unsigned int u; } v; v.f = x;
    unsigned int r = v.u + 0x7FFFu + ((v.u >> 16) & 1u);   // RNE
    return (unsigned short)(r >> 16);
}
static __device__ __forceinline__ float asf(unsigned int u) {
    union { unsigned int u; float f; } v; v.u = u; return v.f;
}
// masked exp(leaky_relu(f1+f2)); scores bounded (~15) -> no softmax shift needed
static __device__ __forceinline__ float wcalc(float f1v, float f2v, int a) {
    const float e = f1v + f2v;
    const float lr = fmaxf(e, ALPHA * e);       // leaky relu as max
    const float w = __expf(lr);
    return (a > 0) ? w : 0.f;
}

// ---- kernel 1: h = X@W -> hb[j/8][col][8] (MFMA B-frag layout), f1, f2 ----
__global__ __launch_bounds__(256) void k_h(
        const float* __restrict__ X, const float* __restrict__ W,
        const float* __restrict__ a1, const float* __restrict__ a2,
        unsigned short* __restrict__ hb,
        float* __restrict__ f1, float* __restrict__ f2) {
    const int lane = threadIdx.x & 63;              // = output column
    const int wave = threadIdx.x >> 6;
    const int row0 = (blockIdx.x * 4 + wave) * 4;   // 4 node-rows per wave

    const float4* Xr[4];
    #pragma unroll
    for (int r = 0; r < 4; ++r)
        Xr[r] = (const float4*)(X + (size_t)(row0 + r) * FIN);

    float acc[4] = {0.f, 0.f, 0.f, 0.f};
    #pragma unroll 4
    for (int k4 = 0; k4 < FIN / 4; ++k4) {
        const float w0 = W[(k4 * 4 + 0) * FOUT + lane];
        const float w1 = W[(k4 * 4 + 1) * FOUT + lane];
        const float w2 = W[(k4 * 4 + 2) * FOUT + lane];
        const float w3 = W[(k4 * 4 + 3) * FOUT + lane];
        #pragma unroll
        for (int r = 0; r < 4; ++r) {
            const float4 xv = Xr[r][k4];
            acc[r] = fmaf(xv.x, w0, acc[r]);
            acc[r] = fmaf(xv.y, w1, acc[r]);
            acc[r] = fmaf(xv.z, w2, acc[r]);
            acc[r] = fmaf(xv.w, w3, acc[r]);
        }
    }

    // hb[chunk=row0>>3][col=lane][e=(row0&7)+r], rows row0..row0+3 same chunk
    ushort4 hv;
    hv.x = f2bf(acc[0]); hv.y = f2bf(acc[1]);
    hv.z = f2bf(acc[2]); hv.w = f2bf(acc[3]);
    *(ushort4*)&hb[(size_t)(row0 >> 3) * 512 + lane * 8 + (row0 & 7)] = hv;

    const float a1v = a1[lane];
    const float a2v = a2[lane];
    #pragma unroll
    for (int r = 0; r < 4; ++r) {
        float p1 = acc[r] * a1v;
        float p2 = acc[r] * a2v;
        #pragma unroll
        for (int off = 32; off > 0; off >>= 1) {
            p1 += __shfl_down(p1, off);
            p2 += __shfl_down(p2, off);
        }
        if (lane == 0) { f1[row0 + r] = p1; f2[row0 + r] = p2; }
    }
}

// -------- kernel 2: barrier-free MFMA attention partial sums --------
// block b: row-group b>>3 (16 rows), j-octant b&7; wave owns 256 j (8 K-steps)
__global__ __launch_bounds__(256) void k_attn(
        const int* __restrict__ adj, const unsigned short* __restrict__ hb,
        const float* __restrict__ f1, const float* __restrict__ f2,
        float* __restrict__ part, float* __restrict__ pden) {
    __shared__ f32x4 red[2][256];    // 8 KB epilogue acc staging
    __shared__ float dred[4][16];

    const int t    = threadIdx.x;
    const int lane = t & 63;
    const int wv   = t >> 6;
    const int bid  = blockIdx.x;
    const int rg   = bid >> 3;
    const int q    = bid & 7;
    const int i0   = rg * 16;
    const int r    = lane & 15;     // A-row / B-col-sub / output col
    const int kg   = lane >> 4;     // k-group within K-step

    const float f1v = f1[i0 + r];
    const int jw = q * JQ + wv * JW;
    const int* aptr = adj + (size_t)(i0 + r) * N + jw + kg * 8;
    const float* f2p = f2 + jw + kg * 8;
    const unsigned short* hbp = hb + (size_t)(jw >> 3) * 512 + kg * 512 + r * 8;

    f32x4 acc[4];
    #pragma unroll
    for (int c = 0; c < 4; ++c) acc[c] = (f32x4){0.f, 0.f, 0.f, 0.f};
    float sacc = 0.f;

    // ping-pong adj prefetch, 2 steps deep (all indices compile-time)
    i32x4 pa0 = *(const i32x4*)(aptr);
    i32x4 pa1 = *(const i32x4*)(aptr + 4);
    i32x4 pb0 = *(const i32x4*)(aptr + 32);
    i32x4 pb1 = *(const i32x4*)(aptr + 36);

    #pragma unroll
    for (int s = 0; s < NS; ++s) {
        i32x4 a0, a1;
        if (s & 1) { a0 = pb0; a1 = pb1; } else { a0 = pa0; a1 = pa1; }
        if (s + 2 < NS) {
            const int* np = aptr + (s + 2) * 32;
            if (s & 1) { pb0 = *(const i32x4*)np; pb1 = *(const i32x4*)(np + 4); }
            else       { pa0 = *(const i32x4*)np; pa1 = *(const i32x4*)(np + 4); }
        }

        // B-fragments: coalesced 16B loads (hb is MFMA-native layout, L2-hot)
        const unsigned short* hs = hbp + s * 2048;
        const bf16x8 b0 = *(const bf16x8*)(hs);
        const bf16x8 b1 = *(const bf16x8*)(hs + 128);
        const bf16x8 b2 = *(const bf16x8*)(hs + 256);
        const bf16x8 b3 = *(const bf16x8*)(hs + 384);

        const float4 fa = *(const float4*)(f2p + s * 32);
        const float4 fb = *(const float4*)(f2p + s * 32 + 4);

        const float w0 = wcalc(f1v, fa.x, a0.x);
        const float w1 = wcalc(f1v, fa.y, a0.y);
        const float w2 = wcalc(f1v, fa.z, a0.z);
        const float w3 = wcalc(f1v, fa.w, a0.w);
        const float w4 = wcalc(f1v, fb.x, a1.x);
        const float w5 = wcalc(f1v, fb.y, a1.y);
        const float w6 = wcalc(f1v, fb.z, a1.z);
        const float w7 = wcalc(f1v, fb.w, a1.w);

        // pack to bf16 pairs (v_cvt_pk_bf16_f32) and build A-frag
        union { bf16x8 v; __hip_bfloat162 h2[4]; unsigned int u[4]; } af;
        af.h2[0] = __float22bfloat162_rn(make_float2(w0, w1));
        af.h2[1] = __float22bfloat162_rn(make_float2(w2, w3));
        af.h2[2] = __float22bfloat162_rn(make_float2(w4, w5));
        af.h2[3] = __float22bfloat162_rn(make_float2(w6, w7));

        // denominator from the ROUNDED weights (bit-extract from packed pairs)
        float ds = 0.f;
        #pragma unroll
        for (int u = 0; u < 4; ++u)
            ds += asf(af.u[u] << 16) + asf(af.u[u] & 0xFFFF0000u);
        sacc += ds;

        acc[0] = __builtin_amdgcn_mfma_f32_16x16x32_bf16(af.v, b0, acc[0], 0, 0, 0);
        acc[1] = __builtin_amdgcn_mfma_f32_16x16x32_bf16(af.v, b1, acc[1], 0, 0, 0);
        acc[2] = __builtin_amdgcn_mfma_f32_16x16x32_bf16(af.v, b2, acc[2], 0, 0, 0);
        acc[3] = __builtin_amdgcn_mfma_f32_16x16x32_bf16(af.v, b3, acc[3], 0, 0, 0);
    }

    // ---- denominator: lanes l, l+16, l+32, l+48 share a row ----
    sacc += __shfl_xor(sacc, 16);
    sacc += __shfl_xor(sacc, 32);
    if (lane < 16) dred[wv][lane] = sacc;

    // ---- acc tree-reduce across the 4 waves ----
    __syncthreads();
    if (wv >= 2) {
        #pragma unroll
        for (int cg = 0; cg < 4; ++cg) red[wv - 2][lane * 4 + cg] = acc[cg];
    }
    __syncthreads();
    if (wv < 2) {
        #pragma unroll
        for (int cg = 0; cg < 4; ++cg) acc[cg] += red[wv][lane * 4 + cg];
    }
    __syncthreads();
    if (wv == 1) {
        #pragma unroll
        for (int cg = 0; cg < 4; ++cg) red[0][lane * 4 + cg] = acc[cg];
    }
    __syncthreads();
    if (wv == 0) {
        #pragma unroll
        for (int cg = 0; cg < 4; ++cg) acc[cg] += red[0][lane * 4 + cg];
        // C/D layout: col = cg*16 + (lane&15), row = (lane>>4)*4 + reg
        #pragma unroll
        for (int cg = 0; cg < 4; ++cg)
            #pragma unroll
            for (int rr = 0; rr < 4; ++rr)
                part[(size_t)bid * 1024 + (kg * 4 + rr) * FOUT + cg * 16 + r]
                    = acc[cg][rr];
        if (lane < 16)
            pden[bid * 16 + lane] =
                dred[0][lane] + dred[1][lane] + dred[2][lane] + dred[3][lane];
    }
}

// -------- kernel 3: combine KQ partials, normalize, ELU --------
__global__ __launch_bounds__(256) void k_fin(
        const float* __restrict__ part, const float* __restrict__ pden,
        float* __restrict__ out) {
    const int rg = blockIdx.x;
    const int t  = threadIdx.x;
    const int r  = t >> 4;
    const int c4 = (t & 15) * 4;

    float4 v = make_float4(0.f, 0.f, 0.f, 0.f);
    float den = 0.f;
    #pragma unroll
    for (int p = 0; p < KQ; ++p) {
        const int blk = rg * KQ + p;
        const float4 pv = *(const float4*)
            &part[(size_t)blk * 1024 + r * FOUT + c4];
        v.x += pv.x; v.y += pv.y; v.z += pv.z; v.w += pv.w;
        den += pden[blk * 16 + r];
    }
    den = fmaxf(den, 1e-30f);
    const float inv = __fdividef(1.f, den);
    float4 o;
    const float h0 = v.x * inv; o.x = (h0 > 0.f) ? h0 : (__expf(h0) - 1.f);
    const float h1 = v.y * inv; o.y = (h1 > 0.f) ? h1 : (__expf(h1) - 1.f);
    const float h2 = v.z * inv; o.z = (h2 > 0.f) ? h2 : (__expf(h2) - 1.f);
    const float h3 = v.w * inv; o.w = (h3 > 0.f) ? h3 : (__expf(h3) - 1.f);
    *(float4*)&out[(size_t)(rg * 16 + r) * FOUT + c4] = o;
}

extern "C" void kernel_launch(void* const* d_in, const int* in_sizes, int n_in,
                              void* d_out, int out_size, void* d_ws, size_t ws_size,
                              hipStream_t stream) {
    const float* X   = (const float*)d_in[0];
    const int*   adj = (const int*)d_in[1];
    const float* W   = (const float*)d_in[2];
    const float* a1  = (const float*)d_in[3];
    const float* a2  = (const float*)d_in[4];
    float* out = (float*)d_out;

    unsigned short* hb = (unsigned short*)d_ws;                   // 1 MB
    float* f1   = (float*)((char*)d_ws + (size_t)FOUT * N * 2);   // N floats
    float* f2   = f1 + N;                                         // N floats
    float* part = f2 + N;                                         // 4096*1024 floats
    float* pden = part + (size_t)(N / 16) * KQ * 1024;            // 4096*16 floats

    k_h   <<<N / 16, 256, 0, stream>>>(X, W, a1, a2, hb, f1, f2);
    k_attn<<<(N / 16) * KQ, 256, 0, stream>>>(adj, hb, f1, f2, part, pden);
    k_fin <<<N / 16, 256, 0, stream>>>(part, pden, out);
}